// Round 3
// baseline (762.989 us; speedup 1.0000x reference)
//
#include <hip/hip_runtime.h>
#include <hip/hip_bf16.h>

#define N_NODES 50000
#define N_PER   12500
#define E_EDGES 600000
#define HDIM    128

// ---------------------------------------------------------------------------
// Count kernel: deg_in[dst]++, deg_out[src]++, cnt_bwd[src]++ if t in {6,14,30}
// ---------------------------------------------------------------------------
__global__ void count_kernel(const int* __restrict__ src, const int* __restrict__ dst,
                             const int* __restrict__ ef,
                             int* __restrict__ deg_in, int* __restrict__ deg_out,
                             int* __restrict__ cnt_bwd) {
    int e = blockIdx.x * blockDim.x + threadIdx.x;
    if (e >= E_EDGES) return;
    int s = src[e], d = dst[e], t = ef[e];
    atomicAdd(&deg_in[d], 1);
    atomicAdd(&deg_out[s], 1);
    if (t == 6 || t == 14 || t == 30) atomicAdd(&cnt_bwd[s], 1);
}

// ---------------------------------------------------------------------------
// Single-block chunked exclusive scan of TWO int arrays + norm computation.
// Each thread owns a contiguous chunk (~49 elems): local sum -> one 1024-wide
// LDS scan (10 steps) -> local prefix rewrite. ~22 barriers total (old
// version: ~1000 serialized barrier rounds -> 122us).
// ---------------------------------------------------------------------------
__global__ __launch_bounds__(1024) void scan_norm_kernel(
    const int* __restrict__ a,        // deg_in
    const int* __restrict__ b,        // cnt_bwd
    const int* __restrict__ deg_out,
    int* __restrict__ offa, int* __restrict__ offb,
    int* __restrict__ cura, int* __restrict__ curb,
    float* __restrict__ onrm, float* __restrict__ inrm, int n) {
    __shared__ int sa[1024];
    __shared__ int sb[1024];
    const int tid = threadIdx.x;
    const int CH = (n + 1023) / 1024;           // 49
    const int i0 = tid * CH;
    const int i1 = min(i0 + CH, n);

    int suma = 0, sumb = 0;
    for (int i = i0; i < i1; ++i) { suma += a[i]; sumb += b[i]; }
    sa[tid] = suma; sb[tid] = sumb;
    __syncthreads();
    for (int off = 1; off < 1024; off <<= 1) {
        int ta = (tid >= off) ? sa[tid - off] : 0;
        int tb = (tid >= off) ? sb[tid - off] : 0;
        __syncthreads();
        sa[tid] += ta; sb[tid] += tb;
        __syncthreads();
    }
    int ea = tid ? sa[tid - 1] : 0;
    int eb = tid ? sb[tid - 1] : 0;
    for (int i = i0; i < i1; ++i) {
        int ai = a[i];
        offa[i] = ea; cura[i] = ea; ea += ai;
        int bi = b[i];
        offb[i] = eb; curb[i] = eb; eb += bi;
        onrm[i] = rsqrtf(fmaxf((float)deg_out[i], 1.0f));
        inrm[i] = rsqrtf(fmaxf((float)ai, 1.0f));
    }
    if (tid == 1023) { offa[n] = sa[1023]; offb[n] = sb[1023]; }
}

// ---------------------------------------------------------------------------
// Fill CSR: forward list keyed by dst (src id packed with weight bit31),
// backward list keyed by src (only t in {6,14,30}), storing dst id.
// ---------------------------------------------------------------------------
__global__ void fill_kernel(const int* __restrict__ src, const int* __restrict__ dst,
                            const int* __restrict__ ef,
                            int* __restrict__ cur_in, int* __restrict__ cur_bwd,
                            int* __restrict__ csr_src, int* __restrict__ csr_bnode) {
    int e = blockIdx.x * blockDim.x + threadIdx.x;
    if (e >= E_EDGES) return;
    int s = src[e], d = dst[e], t = ef[e];
    int p = atomicAdd(&cur_in[d], 1);
    csr_src[p] = s | ((t <= 4) ? 0x80000000 : 0);   // bit31: forward weight == 2
    if (t == 6 || t == 14 || t == 30) {
        int q = atomicAdd(&cur_bwd[s], 1);
        csr_bnode[q] = d;
    }
}

// ---------------------------------------------------------------------------
// Row GEMM: out[r,j] = post(dot(X[r,:],W[:,j])*s1 + b)*s2
// k-outer / rr-inner: 1 LDS W-read (2-way alias, free) + 4 broadcasts per
// 4 FMAs (was 8 LDS reads per 4 FMAs).
// ---------------------------------------------------------------------------
template <int D, bool RELU>
__global__ __launch_bounds__(256) void rowmm_kernel(
    const float* __restrict__ X, const float* __restrict__ W,
    const float* __restrict__ bias, const float* __restrict__ s1,
    const float* __restrict__ s2, float* __restrict__ out, int rows)
{
    constexpr int KT  = 64;
    constexpr int NPB = 8;
    __shared__ float Wl[KT * 128];   // 32 KB
    __shared__ float Xl[NPB][KT];    // 2 KB

    const int tid  = threadIdx.x;
    const int half = tid >> 7;
    const int j    = tid & 127;
    const int base = blockIdx.x * NPB;

    float acc[NPB / 2];
#pragma unroll
    for (int r = 0; r < NPB / 2; ++r) acc[r] = 0.0f;

    for (int kt = 0; kt < D; kt += KT) {
        __syncthreads();
        for (int idx = tid; idx < KT * 128; idx += 256)
            Wl[idx] = W[kt * 128 + idx];
        for (int idx = tid; idx < NPB * KT; idx += 256) {
            int rr = idx / KT, kk = idx % KT;
            int r = base + rr;
            Xl[rr][kk] = (r < rows) ? X[r * D + kt + kk] : 0.0f;
        }
        __syncthreads();

#pragma unroll 4
        for (int k = 0; k < KT; ++k) {
            float w = Wl[k * 128 + j];
#pragma unroll
            for (int rr = 0; rr < NPB / 2; ++rr)
                acc[rr] += Xl[rr * 2 + half][k] * w;
        }
    }

    const float bj = bias[j];
#pragma unroll
    for (int rr = 0; rr < NPB / 2; ++rr) {
        int r = base + rr * 2 + half;
        if (r < rows) {
            float v = acc[rr];
            if (s1) v *= s1[r];
            v += bj;
            if (RELU) v = fmaxf(v, 0.0f);
            if (s2) v *= s2[r];
            out[r * 128 + j] = v;
        }
    }
}

// ---------------------------------------------------------------------------
// Gather aggregation, layer 0 (fused epilogue):
//   B[n] = relu(sum_{e in in(n)} A[src_e] * in_norm[n] + b_g0) * out_norm[n]
// 32 lanes per node, float4 per lane.
// ---------------------------------------------------------------------------
__global__ __launch_bounds__(256) void agg0_kernel(
    const float4* __restrict__ A4, const int* __restrict__ off,
    const int* __restrict__ csr, const float* __restrict__ in_norm,
    const float* __restrict__ b_g0, const float* __restrict__ out_norm,
    float4* __restrict__ B4) {
    int idx = blockIdx.x * blockDim.x + threadIdx.x;
    int n = idx >> 5;
    if (n >= N_NODES) return;
    int j4 = idx & 31;
    int e0 = off[n], e1 = off[n + 1];
    float4 acc = {0.f, 0.f, 0.f, 0.f};
    for (int e = e0; e < e1; ++e) {
        int s = csr[e] & 0x7fffffff;
        float4 v = A4[(size_t)s * 32 + j4];
        acc.x += v.x; acc.y += v.y; acc.z += v.z; acc.w += v.w;
    }
    float innv = in_norm[n], onv = out_norm[n];
    const float4 bg = ((const float4*)b_g0)[j4];
    float4 r;
    r.x = fmaxf(acc.x * innv + bg.x, 0.f) * onv;
    r.y = fmaxf(acc.y * innv + bg.y, 0.f) * onv;
    r.z = fmaxf(acc.z * innv + bg.z, 0.f) * onv;
    r.w = fmaxf(acc.w * innv + bg.w, 0.f) * onv;
    B4[(size_t)n * 32 + j4] = r;
}

// Gather aggregation, plain: B[n] = sum A[src_e]
__global__ __launch_bounds__(256) void agg1_kernel(
    const float4* __restrict__ A4, const int* __restrict__ off,
    const int* __restrict__ csr, float4* __restrict__ B4) {
    int idx = blockIdx.x * blockDim.x + threadIdx.x;
    int n = idx >> 5;
    if (n >= N_NODES) return;
    int j4 = idx & 31;
    int e0 = off[n], e1 = off[n + 1];
    float4 acc = {0.f, 0.f, 0.f, 0.f};
    for (int e = e0; e < e1; ++e) {
        int s = csr[e] & 0x7fffffff;
        float4 v = A4[(size_t)s * 32 + j4];
        acc.x += v.x; acc.y += v.y; acc.z += v.z; acc.w += v.w;
    }
    B4[(size_t)n * 32 + j4] = acc;
}

// ---------------------------------------------------------------------------
// Final gather: out[n] = sum_{fwd in(n)} h[src]*wf + sum_{bwd list(n)} h[dst]
// ---------------------------------------------------------------------------
__global__ __launch_bounds__(256) void final_gather_kernel(
    const float4* __restrict__ H4,
    const int* __restrict__ off_in, const int* __restrict__ csr_src,
    const int* __restrict__ off_bwd, const int* __restrict__ csr_bnode,
    float4* __restrict__ out4) {
    int idx = blockIdx.x * blockDim.x + threadIdx.x;
    int n = idx >> 5;
    if (n >= N_NODES) return;
    int j4 = idx & 31;
    float4 acc = {0.f, 0.f, 0.f, 0.f};
    int e0 = off_in[n], e1 = off_in[n + 1];
    for (int e = e0; e < e1; ++e) {
        int c = csr_src[e];
        int s = c & 0x7fffffff;
        float w = (c < 0) ? 2.0f : 1.0f;
        float4 v = H4[(size_t)s * 32 + j4];
        acc.x += v.x * w; acc.y += v.y * w; acc.z += v.z * w; acc.w += v.w * w;
    }
    int f0 = off_bwd[n], f1 = off_bwd[n + 1];
    for (int e = f0; e < f1; ++e) {
        int d = csr_bnode[e];
        float4 v = H4[(size_t)d * 32 + j4];
        acc.x += v.x; acc.y += v.y; acc.z += v.z; acc.w += v.w;
    }
    out4[(size_t)n * 32 + j4] = acc;
}

extern "C" void kernel_launch(void* const* d_in, const int* in_sizes, int n_in,
                              void* d_out, int out_size, void* d_ws, size_t ws_size,
                              hipStream_t stream) {
    const float* feat[4]  = {(const float*)d_in[0], (const float*)d_in[3],
                             (const float*)d_in[6], (const float*)d_in[9]};
    const float* W_fc[4]  = {(const float*)d_in[1], (const float*)d_in[4],
                             (const float*)d_in[7], (const float*)d_in[10]};
    const float* b_fc[4]  = {(const float*)d_in[2], (const float*)d_in[5],
                             (const float*)d_in[8], (const float*)d_in[11]};
    const int*   src      = (const int*)d_in[12];
    const int*   dst      = (const int*)d_in[13];
    const int*   efeat    = (const int*)d_in[14];
    const float* b_g0     = (const float*)d_in[15];
    const float* W_g1     = (const float*)d_in[16];
    const float* b_g1     = (const float*)d_in[17];
    float* out = (float*)d_out;

    // Workspace layout (floats then ints), ~58 MB total.
    float* A        = (float*)d_ws;                       // 6.4M
    float* B        = A + (size_t)N_NODES * HDIM;         // 6.4M
    float* out_norm = B + (size_t)N_NODES * HDIM;         // 50k
    float* in_norm  = out_norm + N_NODES;                 // 50k
    int* deg_in    = (int*)(in_norm + N_NODES);           // 50k
    int* deg_out   = deg_in + N_NODES;                    // 50k
    int* cnt_bwd   = deg_out + N_NODES;                   // 50k
    int* off_in    = cnt_bwd + N_NODES;                   // 50k+1
    int* off_bwd   = off_in + N_NODES + 1;                // 50k+1
    int* cur_in    = off_bwd + N_NODES + 1;               // 50k
    int* cur_bwd   = cur_in + N_NODES;                    // 50k
    int* csr_src   = cur_bwd + N_NODES;                   // 600k
    int* csr_bnode = csr_src + E_EDGES;                   // 600k

    // 1) CSR build + norms
    hipMemsetAsync(deg_in, 0, 3 * (size_t)N_NODES * sizeof(int), stream);
    count_kernel<<<(E_EDGES + 255) / 256, 256, 0, stream>>>(src, dst, efeat,
                                                            deg_in, deg_out, cnt_bwd);
    scan_norm_kernel<<<1, 1024, 0, stream>>>(deg_in, cnt_bwd, deg_out,
                                             off_in, off_bwd, cur_in, cur_bwd,
                                             out_norm, in_norm, N_NODES);
    fill_kernel<<<(E_EDGES + 255) / 256, 256, 0, stream>>>(src, dst, efeat,
                                                           cur_in, cur_bwd,
                                                           csr_src, csr_bnode);

    // 2) per-type FC: A = (feat @ W + b) * out_norm
    const int grid_fc = (N_PER + 7) / 8;
    rowmm_kernel<128, false><<<grid_fc, 256, 0, stream>>>(
        feat[0], W_fc[0], b_fc[0], nullptr, out_norm + 0 * N_PER,
        A + (size_t)0 * N_PER * HDIM, N_PER);
    rowmm_kernel<128, false><<<grid_fc, 256, 0, stream>>>(
        feat[1], W_fc[1], b_fc[1], nullptr, out_norm + 1 * N_PER,
        A + (size_t)1 * N_PER * HDIM, N_PER);
    rowmm_kernel<64, false><<<grid_fc, 256, 0, stream>>>(
        feat[2], W_fc[2], b_fc[2], nullptr, out_norm + 2 * N_PER,
        A + (size_t)2 * N_PER * HDIM, N_PER);
    rowmm_kernel<64, false><<<grid_fc, 256, 0, stream>>>(
        feat[3], W_fc[3], b_fc[3], nullptr, out_norm + 3 * N_PER,
        A + (size_t)3 * N_PER * HDIM, N_PER);

    const int grid_node = (N_NODES * 32 + 255) / 256;

    // 3) layer0: gather A -> epilogue -> B (pre-scaled by out_norm for layer1)
    agg0_kernel<<<grid_node, 256, 0, stream>>>((const float4*)A, off_in, csr_src,
                                               in_norm, b_g0, out_norm, (float4*)B);
    // 4) layer1: gather B -> A (raw), then rowmm: B = relu((A @ W_g1)*in_norm + b_g1)
    agg1_kernel<<<grid_node, 256, 0, stream>>>((const float4*)B, off_in, csr_src,
                                               (float4*)A);
    rowmm_kernel<128, true><<<(N_NODES + 7) / 8, 256, 0, stream>>>(
        A, W_g1, b_g1, in_norm, nullptr, B, N_NODES);

    // 5) final edge-typed gather into d_out (writes every element; no memset)
    final_gather_kernel<<<grid_node, 256, 0, stream>>>((const float4*)B,
                                                       off_in, csr_src,
                                                       off_bwd, csr_bnode,
                                                       (float4*)out);
}

// Round 4
// 476.335 us; speedup vs baseline: 1.6018x; 1.6018x over previous
//
#include <hip/hip_runtime.h>
#include <hip/hip_bf16.h>

#define N_NODES 50000
#define N_PER   12500
#define E_EDGES 600000
#define HDIM    128

#define SCAN_TILE 1024
#define SCAN_NBLK ((N_NODES + SCAN_TILE - 1) / SCAN_TILE)   // 49

// ---------------------------------------------------------------------------
// Count kernel: deg_in[dst]++, deg_out[src]++, cnt_bwd[src]++ if t in {6,14,30}
// ---------------------------------------------------------------------------
__global__ void count_kernel(const int* __restrict__ src, const int* __restrict__ dst,
                             const int* __restrict__ ef,
                             int* __restrict__ deg_in, int* __restrict__ deg_out,
                             int* __restrict__ cnt_bwd) {
    int e = blockIdx.x * blockDim.x + threadIdx.x;
    if (e >= E_EDGES) return;
    int s = src[e], d = dst[e], t = ef[e];
    atomicAdd(&deg_in[d], 1);
    atomicAdd(&deg_out[s], 1);
    if (t == 6 || t == 14 || t == 30) atomicAdd(&cnt_bwd[s], 1);
}

// ---------------------------------------------------------------------------
// Hierarchical scan phase 1: per-block exclusive scan of two arrays.
// 1024 elems/block; coalesced loads/stores via LDS; 8-step block scan.
// ---------------------------------------------------------------------------
__global__ __launch_bounds__(256) void scan1_kernel(
    const int* __restrict__ a, const int* __restrict__ b,
    int* __restrict__ tmpa, int* __restrict__ tmpb,
    int* __restrict__ bsumA, int* __restrict__ bsumB, int n) {
    __shared__ int la[SCAN_TILE];
    __shared__ int lb[SCAN_TILE];
    __shared__ int ssa[256];
    __shared__ int ssb[256];
    const int tid = threadIdx.x;
    const int base = blockIdx.x * SCAN_TILE;

#pragma unroll
    for (int k = 0; k < 4; ++k) {
        int i = base + k * 256 + tid;
        la[k * 256 + tid] = (i < n) ? a[i] : 0;
        lb[k * 256 + tid] = (i < n) ? b[i] : 0;
    }
    __syncthreads();

    // thread-local scan of 4 contiguous LDS elems
    int pa[4], pb[4], sa = 0, sb = 0;
#pragma unroll
    for (int e = 0; e < 4; ++e) {
        pa[e] = sa; sa += la[tid * 4 + e];
        pb[e] = sb; sb += lb[tid * 4 + e];
    }
    ssa[tid] = sa; ssb[tid] = sb;
    __syncthreads();
    for (int off = 1; off < 256; off <<= 1) {
        int ta = (tid >= off) ? ssa[tid - off] : 0;
        int tb = (tid >= off) ? ssb[tid - off] : 0;
        __syncthreads();
        ssa[tid] += ta; ssb[tid] += tb;
        __syncthreads();
    }
    int ea = tid ? ssa[tid - 1] : 0;
    int eb = tid ? ssb[tid - 1] : 0;
    __syncthreads();
#pragma unroll
    for (int e = 0; e < 4; ++e) {
        la[tid * 4 + e] = ea + pa[e];
        lb[tid * 4 + e] = eb + pb[e];
    }
    __syncthreads();
#pragma unroll
    for (int k = 0; k < 4; ++k) {
        int i = base + k * 256 + tid;
        if (i < n) {
            tmpa[i] = la[k * 256 + tid];
            tmpb[i] = lb[k * 256 + tid];
        }
    }
    if (tid == 255) {
        bsumA[blockIdx.x] = ssa[255];
        bsumB[blockIdx.x] = ssb[255];
    }
}

// Phase 2: one wave scans the block sums (exclusive) and writes totals.
__global__ __launch_bounds__(64) void scan2_kernel(
    int* __restrict__ bsumA, int* __restrict__ bsumB,
    int* __restrict__ boffA, int* __restrict__ boffB,
    int* __restrict__ offa, int* __restrict__ offb, int nblk, int n) {
    __shared__ int sa[64], sb[64];
    const int tid = threadIdx.x;
    sa[tid] = (tid < nblk) ? bsumA[tid] : 0;
    sb[tid] = (tid < nblk) ? bsumB[tid] : 0;
    __syncthreads();
    for (int off = 1; off < 64; off <<= 1) {
        int ta = (tid >= off) ? sa[tid - off] : 0;
        int tb = (tid >= off) ? sb[tid - off] : 0;
        __syncthreads();
        sa[tid] += ta; sb[tid] += tb;
        __syncthreads();
    }
    if (tid < nblk) {
        boffA[tid] = tid ? sa[tid - 1] : 0;
        boffB[tid] = tid ? sb[tid - 1] : 0;
    }
    if (tid == 63) { offa[n] = sa[63]; offb[n] = sb[63]; }
}

// Phase 3: add block offsets, write off/cur arrays + both norms (coalesced).
__global__ __launch_bounds__(256) void scan3_kernel(
    const int* __restrict__ tmpa, const int* __restrict__ tmpb,
    const int* __restrict__ boffA, const int* __restrict__ boffB,
    const int* __restrict__ deg_in, const int* __restrict__ deg_out,
    int* __restrict__ offa, int* __restrict__ offb,
    int* __restrict__ cura, int* __restrict__ curb,
    float* __restrict__ onrm, float* __restrict__ inrm, int n) {
    const int base = blockIdx.x * SCAN_TILE;
    const int ba = boffA[blockIdx.x], bb = boffB[blockIdx.x];
#pragma unroll
    for (int k = 0; k < 4; ++k) {
        int i = base + k * 256 + threadIdx.x;
        if (i < n) {
            int va = tmpa[i] + ba;
            int vb = tmpb[i] + bb;
            offa[i] = va; cura[i] = va;
            offb[i] = vb; curb[i] = vb;
            onrm[i] = rsqrtf(fmaxf((float)deg_out[i], 1.0f));
            inrm[i] = rsqrtf(fmaxf((float)deg_in[i], 1.0f));
        }
    }
}

// ---------------------------------------------------------------------------
// Fill CSR: forward list keyed by dst (src id packed with weight bit31),
// backward list keyed by src (only t in {6,14,30}), storing dst id.
// ---------------------------------------------------------------------------
__global__ void fill_kernel(const int* __restrict__ src, const int* __restrict__ dst,
                            const int* __restrict__ ef,
                            int* __restrict__ cur_in, int* __restrict__ cur_bwd,
                            int* __restrict__ csr_src, int* __restrict__ csr_bnode) {
    int e = blockIdx.x * blockDim.x + threadIdx.x;
    if (e >= E_EDGES) return;
    int s = src[e], d = dst[e], t = ef[e];
    int p = atomicAdd(&cur_in[d], 1);
    csr_src[p] = s | ((t <= 4) ? 0x80000000 : 0);   // bit31: forward weight == 2
    if (t == 6 || t == 14 || t == 30) {
        int q = atomicAdd(&cur_bwd[s], 1);
        csr_bnode[q] = d;
    }
}

// ---------------------------------------------------------------------------
// Row GEMM: out[r,j] = post(dot(X[r,:],W[:,j])*s1 + b)*s2
// ---------------------------------------------------------------------------
template <int D, bool RELU>
__global__ __launch_bounds__(256) void rowmm_kernel(
    const float* __restrict__ X, const float* __restrict__ W,
    const float* __restrict__ bias, const float* __restrict__ s1,
    const float* __restrict__ s2, float* __restrict__ out, int rows)
{
    constexpr int KT  = 64;
    constexpr int NPB = 8;
    __shared__ float Wl[KT * 128];   // 32 KB
    __shared__ float Xl[NPB][KT];    // 2 KB

    const int tid  = threadIdx.x;
    const int half = tid >> 7;
    const int j    = tid & 127;
    const int base = blockIdx.x * NPB;

    float acc[NPB / 2];
#pragma unroll
    for (int r = 0; r < NPB / 2; ++r) acc[r] = 0.0f;

    for (int kt = 0; kt < D; kt += KT) {
        __syncthreads();
        for (int idx = tid; idx < KT * 128; idx += 256)
            Wl[idx] = W[kt * 128 + idx];
        for (int idx = tid; idx < NPB * KT; idx += 256) {
            int rr = idx / KT, kk = idx % KT;
            int r = base + rr;
            Xl[rr][kk] = (r < rows) ? X[r * D + kt + kk] : 0.0f;
        }
        __syncthreads();

#pragma unroll 4
        for (int k = 0; k < KT; ++k) {
            float w = Wl[k * 128 + j];
#pragma unroll
            for (int rr = 0; rr < NPB / 2; ++rr)
                acc[rr] += Xl[rr * 2 + half][k] * w;
        }
    }

    const float bj = bias[j];
#pragma unroll
    for (int rr = 0; rr < NPB / 2; ++rr) {
        int r = base + rr * 2 + half;
        if (r < rows) {
            float v = acc[rr];
            if (s1) v *= s1[r];
            v += bj;
            if (RELU) v = fmaxf(v, 0.0f);
            if (s2) v *= s2[r];
            out[r * 128 + j] = v;
        }
    }
}

// ---------------------------------------------------------------------------
// Gather aggregation, layer 0 (fused epilogue):
//   B[n] = relu(sum_{e in in(n)} A[src_e] * in_norm[n] + b_g0) * out_norm[n]
// ---------------------------------------------------------------------------
__global__ __launch_bounds__(256) void agg0_kernel(
    const float4* __restrict__ A4, const int* __restrict__ off,
    const int* __restrict__ csr, const float* __restrict__ in_norm,
    const float* __restrict__ b_g0, const float* __restrict__ out_norm,
    float4* __restrict__ B4) {
    int idx = blockIdx.x * blockDim.x + threadIdx.x;
    int n = idx >> 5;
    if (n >= N_NODES) return;
    int j4 = idx & 31;
    int e0 = off[n], e1 = off[n + 1];
    float4 acc = {0.f, 0.f, 0.f, 0.f};
    for (int e = e0; e < e1; ++e) {
        int s = csr[e] & 0x7fffffff;
        float4 v = A4[(size_t)s * 32 + j4];
        acc.x += v.x; acc.y += v.y; acc.z += v.z; acc.w += v.w;
    }
    float innv = in_norm[n], onv = out_norm[n];
    const float4 bg = ((const float4*)b_g0)[j4];
    float4 r;
    r.x = fmaxf(acc.x * innv + bg.x, 0.f) * onv;
    r.y = fmaxf(acc.y * innv + bg.y, 0.f) * onv;
    r.z = fmaxf(acc.z * innv + bg.z, 0.f) * onv;
    r.w = fmaxf(acc.w * innv + bg.w, 0.f) * onv;
    B4[(size_t)n * 32 + j4] = r;
}

// Gather aggregation, plain: B[n] = sum A[src_e]
__global__ __launch_bounds__(256) void agg1_kernel(
    const float4* __restrict__ A4, const int* __restrict__ off,
    const int* __restrict__ csr, float4* __restrict__ B4) {
    int idx = blockIdx.x * blockDim.x + threadIdx.x;
    int n = idx >> 5;
    if (n >= N_NODES) return;
    int j4 = idx & 31;
    int e0 = off[n], e1 = off[n + 1];
    float4 acc = {0.f, 0.f, 0.f, 0.f};
    for (int e = e0; e < e1; ++e) {
        int s = csr[e] & 0x7fffffff;
        float4 v = A4[(size_t)s * 32 + j4];
        acc.x += v.x; acc.y += v.y; acc.z += v.z; acc.w += v.w;
    }
    B4[(size_t)n * 32 + j4] = acc;
}

// ---------------------------------------------------------------------------
// Final gather: out[n] = sum_{fwd in(n)} h[src]*wf + sum_{bwd list(n)} h[dst]
// ---------------------------------------------------------------------------
__global__ __launch_bounds__(256) void final_gather_kernel(
    const float4* __restrict__ H4,
    const int* __restrict__ off_in, const int* __restrict__ csr_src,
    const int* __restrict__ off_bwd, const int* __restrict__ csr_bnode,
    float4* __restrict__ out4) {
    int idx = blockIdx.x * blockDim.x + threadIdx.x;
    int n = idx >> 5;
    if (n >= N_NODES) return;
    int j4 = idx & 31;
    float4 acc = {0.f, 0.f, 0.f, 0.f};
    int e0 = off_in[n], e1 = off_in[n + 1];
    for (int e = e0; e < e1; ++e) {
        int c = csr_src[e];
        int s = c & 0x7fffffff;
        float w = (c < 0) ? 2.0f : 1.0f;
        float4 v = H4[(size_t)s * 32 + j4];
        acc.x += v.x * w; acc.y += v.y * w; acc.z += v.z * w; acc.w += v.w * w;
    }
    int f0 = off_bwd[n], f1 = off_bwd[n + 1];
    for (int e = f0; e < f1; ++e) {
        int d = csr_bnode[e];
        float4 v = H4[(size_t)d * 32 + j4];
        acc.x += v.x; acc.y += v.y; acc.z += v.z; acc.w += v.w;
    }
    out4[(size_t)n * 32 + j4] = acc;
}

extern "C" void kernel_launch(void* const* d_in, const int* in_sizes, int n_in,
                              void* d_out, int out_size, void* d_ws, size_t ws_size,
                              hipStream_t stream) {
    const float* feat[4]  = {(const float*)d_in[0], (const float*)d_in[3],
                             (const float*)d_in[6], (const float*)d_in[9]};
    const float* W_fc[4]  = {(const float*)d_in[1], (const float*)d_in[4],
                             (const float*)d_in[7], (const float*)d_in[10]};
    const float* b_fc[4]  = {(const float*)d_in[2], (const float*)d_in[5],
                             (const float*)d_in[8], (const float*)d_in[11]};
    const int*   src      = (const int*)d_in[12];
    const int*   dst      = (const int*)d_in[13];
    const int*   efeat    = (const int*)d_in[14];
    const float* b_g0     = (const float*)d_in[15];
    const float* W_g1     = (const float*)d_in[16];
    const float* b_g1     = (const float*)d_in[17];
    float* out = (float*)d_out;

    // Workspace layout (floats then ints), ~59 MB total.
    float* A        = (float*)d_ws;                       // 6.4M
    float* B        = A + (size_t)N_NODES * HDIM;         // 6.4M
    float* out_norm = B + (size_t)N_NODES * HDIM;         // 50k
    float* in_norm  = out_norm + N_NODES;                 // 50k
    int* deg_in    = (int*)(in_norm + N_NODES);           // 50k
    int* deg_out   = deg_in + N_NODES;                    // 50k
    int* cnt_bwd   = deg_out + N_NODES;                   // 50k
    int* off_in    = cnt_bwd + N_NODES;                   // 50k+1
    int* off_bwd   = off_in + N_NODES + 1;                // 50k+1
    int* cur_in    = off_bwd + N_NODES + 1;               // 50k
    int* cur_bwd   = cur_in + N_NODES;                    // 50k
    int* csr_src   = cur_bwd + N_NODES;                   // 600k
    int* csr_bnode = csr_src + E_EDGES;                   // 600k
    int* tmpa      = csr_bnode + E_EDGES;                 // 50k
    int* tmpb      = tmpa + N_NODES;                      // 50k
    int* bsumA     = tmpb + N_NODES;                      // 64
    int* bsumB     = bsumA + 64;                          // 64
    int* boffA     = bsumB + 64;                          // 64
    int* boffB     = boffA + 64;                          // 64

    // 1) CSR build + norms (hierarchical scan, all coalesced)
    hipMemsetAsync(deg_in, 0, 3 * (size_t)N_NODES * sizeof(int), stream);
    count_kernel<<<(E_EDGES + 255) / 256, 256, 0, stream>>>(src, dst, efeat,
                                                            deg_in, deg_out, cnt_bwd);
    scan1_kernel<<<SCAN_NBLK, 256, 0, stream>>>(deg_in, cnt_bwd, tmpa, tmpb,
                                                bsumA, bsumB, N_NODES);
    scan2_kernel<<<1, 64, 0, stream>>>(bsumA, bsumB, boffA, boffB,
                                       off_in, off_bwd, SCAN_NBLK, N_NODES);
    scan3_kernel<<<SCAN_NBLK, 256, 0, stream>>>(tmpa, tmpb, boffA, boffB,
                                                deg_in, deg_out,
                                                off_in, off_bwd, cur_in, cur_bwd,
                                                out_norm, in_norm, N_NODES);
    fill_kernel<<<(E_EDGES + 255) / 256, 256, 0, stream>>>(src, dst, efeat,
                                                           cur_in, cur_bwd,
                                                           csr_src, csr_bnode);

    // 2) per-type FC: A = (feat @ W + b) * out_norm
    const int grid_fc = (N_PER + 7) / 8;
    rowmm_kernel<128, false><<<grid_fc, 256, 0, stream>>>(
        feat[0], W_fc[0], b_fc[0], nullptr, out_norm + 0 * N_PER,
        A + (size_t)0 * N_PER * HDIM, N_PER);
    rowmm_kernel<128, false><<<grid_fc, 256, 0, stream>>>(
        feat[1], W_fc[1], b_fc[1], nullptr, out_norm + 1 * N_PER,
        A + (size_t)1 * N_PER * HDIM, N_PER);
    rowmm_kernel<64, false><<<grid_fc, 256, 0, stream>>>(
        feat[2], W_fc[2], b_fc[2], nullptr, out_norm + 2 * N_PER,
        A + (size_t)2 * N_PER * HDIM, N_PER);
    rowmm_kernel<64, false><<<grid_fc, 256, 0, stream>>>(
        feat[3], W_fc[3], b_fc[3], nullptr, out_norm + 3 * N_PER,
        A + (size_t)3 * N_PER * HDIM, N_PER);

    const int grid_node = (N_NODES * 32 + 255) / 256;

    // 3) layer0: gather A -> epilogue -> B (pre-scaled by out_norm for layer1)
    agg0_kernel<<<grid_node, 256, 0, stream>>>((const float4*)A, off_in, csr_src,
                                               in_norm, b_g0, out_norm, (float4*)B);
    // 4) layer1: gather B -> A (raw), then rowmm: B = relu((A @ W_g1)*in_norm + b_g1)
    agg1_kernel<<<grid_node, 256, 0, stream>>>((const float4*)B, off_in, csr_src,
                                               (float4*)A);
    rowmm_kernel<128, true><<<(N_NODES + 7) / 8, 256, 0, stream>>>(
        A, W_g1, b_g1, in_norm, nullptr, B, N_NODES);

    // 5) final edge-typed gather into d_out (writes every element; no memset)
    final_gather_kernel<<<grid_node, 256, 0, stream>>>((const float4*)B,
                                                       off_in, csr_src,
                                                       off_bwd, csr_bnode,
                                                       (float4*)out);
}

// Round 5
// 363.949 us; speedup vs baseline: 2.0964x; 1.3088x over previous
//
#include <hip/hip_runtime.h>
#include <hip/hip_bf16.h>

#define N_NODES 50000
#define N_PER   12500
#define E_EDGES 600000
#define HDIM    128

#define SCAN_TILE 1024
#define SCAN_NBLK ((N_NODES + SCAN_TILE - 1) / SCAN_TILE)   // 49

typedef __attribute__((ext_vector_type(8))) short bfrag;   // 8 bf16 (4 VGPRs)
typedef __attribute__((ext_vector_type(4))) float ffrag;   // 4 fp32 acc

__device__ __forceinline__ unsigned short f2bf(float f) {
    union { float f; unsigned u; } x; x.f = f;
    unsigned r = x.u + 0x7fffu + ((x.u >> 16) & 1u);   // RTNE
    return (unsigned short)(r >> 16);
}
__device__ __forceinline__ float lo_bf(unsigned v) { return __uint_as_float(v << 16); }
__device__ __forceinline__ float hi_bf(unsigned v) { return __uint_as_float(v & 0xffff0000u); }
__device__ __forceinline__ unsigned pack2(float a, float b) {
    return (unsigned)f2bf(a) | ((unsigned)f2bf(b) << 16);
}

// ---------------------------------------------------------------------------
// CSR build (unchanged from R4)
// ---------------------------------------------------------------------------
__global__ void count_kernel(const int* __restrict__ src, const int* __restrict__ dst,
                             const int* __restrict__ ef,
                             int* __restrict__ deg_in, int* __restrict__ deg_out,
                             int* __restrict__ cnt_bwd) {
    int e = blockIdx.x * blockDim.x + threadIdx.x;
    if (e >= E_EDGES) return;
    int s = src[e], d = dst[e], t = ef[e];
    atomicAdd(&deg_in[d], 1);
    atomicAdd(&deg_out[s], 1);
    if (t == 6 || t == 14 || t == 30) atomicAdd(&cnt_bwd[s], 1);
}

__global__ __launch_bounds__(256) void scan1_kernel(
    const int* __restrict__ a, const int* __restrict__ b,
    int* __restrict__ tmpa, int* __restrict__ tmpb,
    int* __restrict__ bsumA, int* __restrict__ bsumB, int n) {
    __shared__ int la[SCAN_TILE];
    __shared__ int lb[SCAN_TILE];
    __shared__ int ssa[256];
    __shared__ int ssb[256];
    const int tid = threadIdx.x;
    const int base = blockIdx.x * SCAN_TILE;
#pragma unroll
    for (int k = 0; k < 4; ++k) {
        int i = base + k * 256 + tid;
        la[k * 256 + tid] = (i < n) ? a[i] : 0;
        lb[k * 256 + tid] = (i < n) ? b[i] : 0;
    }
    __syncthreads();
    int pa[4], pb[4], sa = 0, sb = 0;
#pragma unroll
    for (int e = 0; e < 4; ++e) {
        pa[e] = sa; sa += la[tid * 4 + e];
        pb[e] = sb; sb += lb[tid * 4 + e];
    }
    ssa[tid] = sa; ssb[tid] = sb;
    __syncthreads();
    for (int off = 1; off < 256; off <<= 1) {
        int ta = (tid >= off) ? ssa[tid - off] : 0;
        int tb = (tid >= off) ? ssb[tid - off] : 0;
        __syncthreads();
        ssa[tid] += ta; ssb[tid] += tb;
        __syncthreads();
    }
    int ea = tid ? ssa[tid - 1] : 0;
    int eb = tid ? ssb[tid - 1] : 0;
    __syncthreads();
#pragma unroll
    for (int e = 0; e < 4; ++e) {
        la[tid * 4 + e] = ea + pa[e];
        lb[tid * 4 + e] = eb + pb[e];
    }
    __syncthreads();
#pragma unroll
    for (int k = 0; k < 4; ++k) {
        int i = base + k * 256 + tid;
        if (i < n) { tmpa[i] = la[k * 256 + tid]; tmpb[i] = lb[k * 256 + tid]; }
    }
    if (tid == 255) { bsumA[blockIdx.x] = ssa[255]; bsumB[blockIdx.x] = ssb[255]; }
}

__global__ __launch_bounds__(64) void scan2_kernel(
    int* __restrict__ bsumA, int* __restrict__ bsumB,
    int* __restrict__ boffA, int* __restrict__ boffB,
    int* __restrict__ offa, int* __restrict__ offb, int nblk, int n) {
    __shared__ int sa[64], sb[64];
    const int tid = threadIdx.x;
    sa[tid] = (tid < nblk) ? bsumA[tid] : 0;
    sb[tid] = (tid < nblk) ? bsumB[tid] : 0;
    __syncthreads();
    for (int off = 1; off < 64; off <<= 1) {
        int ta = (tid >= off) ? sa[tid - off] : 0;
        int tb = (tid >= off) ? sb[tid - off] : 0;
        __syncthreads();
        sa[tid] += ta; sb[tid] += tb;
        __syncthreads();
    }
    if (tid < nblk) {
        boffA[tid] = tid ? sa[tid - 1] : 0;
        boffB[tid] = tid ? sb[tid - 1] : 0;
    }
    if (tid == 63) { offa[n] = sa[63]; offb[n] = sb[63]; }
}

__global__ __launch_bounds__(256) void scan3_kernel(
    const int* __restrict__ tmpa, const int* __restrict__ tmpb,
    const int* __restrict__ boffA, const int* __restrict__ boffB,
    const int* __restrict__ deg_in, const int* __restrict__ deg_out,
    int* __restrict__ offa, int* __restrict__ offb,
    int* __restrict__ cura, int* __restrict__ curb,
    float* __restrict__ onrm, float* __restrict__ inrm, int n) {
    const int base = blockIdx.x * SCAN_TILE;
    const int ba = boffA[blockIdx.x], bb = boffB[blockIdx.x];
#pragma unroll
    for (int k = 0; k < 4; ++k) {
        int i = base + k * 256 + threadIdx.x;
        if (i < n) {
            int va = tmpa[i] + ba;
            int vb = tmpb[i] + bb;
            offa[i] = va; cura[i] = va;
            offb[i] = vb; curb[i] = vb;
            onrm[i] = rsqrtf(fmaxf((float)deg_out[i], 1.0f));
            inrm[i] = rsqrtf(fmaxf((float)deg_in[i], 1.0f));
        }
    }
}

__global__ void fill_kernel(const int* __restrict__ src, const int* __restrict__ dst,
                            const int* __restrict__ ef,
                            int* __restrict__ cur_in, int* __restrict__ cur_bwd,
                            int* __restrict__ csr_src, int* __restrict__ csr_bnode) {
    int e = blockIdx.x * blockDim.x + threadIdx.x;
    if (e >= E_EDGES) return;
    int s = src[e], d = dst[e], t = ef[e];
    int p = atomicAdd(&cur_in[d], 1);
    csr_src[p] = s | ((t <= 4) ? 0x80000000 : 0);   // bit31: forward weight == 2
    if (t == 6 || t == 14 || t == 30) {
        int q = atomicAdd(&cur_bwd[s], 1);
        csr_bnode[q] = d;
    }
}

// ---------------------------------------------------------------------------
// Pack W (D x 128 fp32 row-major) into MFMA B-fragment order, bf16:
//   Wp[((n0*KT + kt)*64 + lane)*8 + j] = W[(kt*32 + (lane>>4)*8 + j)*128 + n0*16 + (lane&15)]
// ---------------------------------------------------------------------------
__global__ void prepw_kernel(const float* __restrict__ W, unsigned short* __restrict__ Wp,
                             int D) {
    int KT = D / 32;
    int tid = blockIdx.x * blockDim.x + threadIdx.x;
    if (tid >= 8 * KT * 64) return;
    int l = tid & 63;
    int t = tid >> 6;
    int kt = t % KT, n0 = t / KT;
    int n = n0 * 16 + (l & 15);
    int kb = kt * 32 + (l >> 4) * 8;
#pragma unroll
    for (int j = 0; j < 8; ++j)
        Wp[(size_t)tid * 8 + j] = f2bf(W[(size_t)(kb + j) * 128 + n]);
}

// ---------------------------------------------------------------------------
// MFMA GEMM: C = X(rows x D) @ W(D x 128), epilogue -> bf16 out (rows x 128).
//   MODE 0 (FC):  v = (c + bias[col]) * s[row]
//   MODE 1 (big): v = relu(c * s[row] + bias[col])
// Block = 4 waves; wave computes a 16-row strip (8 col-tiles of 16x16).
// A-layout: lane holds A[m=lane&15][k=q*8+j]; C/D: col=lane&15, row=q*4+reg.
// ---------------------------------------------------------------------------
template<int D, int MODE, bool XF32>
__global__ __launch_bounds__(256) void mfma_gemm_kernel(
    const void* __restrict__ Xv,
    const unsigned short* __restrict__ Wp,
    const float* __restrict__ bias,
    const float* __restrict__ s,
    unsigned short* __restrict__ outbf,
    int rows)
{
    constexpr int KT = D / 32;
    const int lane = threadIdx.x & 63;
    const int wave = threadIdx.x >> 6;
    const int m = lane & 15, q = lane >> 4;
    const int rbase = blockIdx.x * 64 + wave * 16;
    const int row = rbase + m;

    bfrag afr[KT];
#pragma unroll
    for (int kt = 0; kt < KT; ++kt) {
        bfrag a;
        if (row < rows) {
            if (XF32) {
                const float* xp = (const float*)Xv + (size_t)row * D + kt * 32 + q * 8;
                float4 u0 = *(const float4*)xp;
                float4 u1 = *(const float4*)(xp + 4);
                a[0] = (short)f2bf(u0.x); a[1] = (short)f2bf(u0.y);
                a[2] = (short)f2bf(u0.z); a[3] = (short)f2bf(u0.w);
                a[4] = (short)f2bf(u1.x); a[5] = (short)f2bf(u1.y);
                a[6] = (short)f2bf(u1.z); a[7] = (short)f2bf(u1.w);
            } else {
                a = *(const bfrag*)((const unsigned short*)Xv +
                                    (size_t)row * D + kt * 32 + q * 8);
            }
        } else {
#pragma unroll
            for (int t = 0; t < 8; ++t) a[t] = 0;
        }
        afr[kt] = a;
    }

    ffrag acc[8];
#pragma unroll
    for (int n0 = 0; n0 < 8; ++n0) {
#pragma unroll
        for (int t = 0; t < 4; ++t) acc[n0][t] = 0.f;
    }

#pragma unroll
    for (int n0 = 0; n0 < 8; ++n0) {
#pragma unroll
        for (int kt = 0; kt < KT; ++kt) {
            bfrag bfr = *(const bfrag*)(Wp + ((size_t)(n0 * KT + kt) * 64 + lane) * 8);
            acc[n0] = __builtin_amdgcn_mfma_f32_16x16x32_bf16(afr[kt], bfr, acc[n0], 0, 0, 0);
        }
    }

    // Epilogue: lane writes col = n0*16 + m, rows rbase + q*4 + r.
#pragma unroll
    for (int n0 = 0; n0 < 8; ++n0) {
        const int col = n0 * 16 + m;
        const float bj = bias[col];
#pragma unroll
        for (int r = 0; r < 4; ++r) {
            int orow = rbase + q * 4 + r;
            if (orow < rows) {
                float c = acc[n0][r];
                float v;
                if (MODE == 0) v = (c + bj) * s[orow];
                else           v = fmaxf(c * s[orow] + bj, 0.f);
                outbf[(size_t)orow * 128 + col] = f2bf(v);
            }
        }
    }
}

// ---------------------------------------------------------------------------
// Gather aggregations over bf16 rows: 16 lanes/node, uint4 (8 bf16) per lane.
// ---------------------------------------------------------------------------
__device__ __forceinline__ void acc8_add(float* acc, uint4 v) {
    acc[0] += lo_bf(v.x); acc[1] += hi_bf(v.x);
    acc[2] += lo_bf(v.y); acc[3] += hi_bf(v.y);
    acc[4] += lo_bf(v.z); acc[5] += hi_bf(v.z);
    acc[6] += lo_bf(v.w); acc[7] += hi_bf(v.w);
}
__device__ __forceinline__ void acc8_addw(float* acc, uint4 v, float w) {
    acc[0] += lo_bf(v.x) * w; acc[1] += hi_bf(v.x) * w;
    acc[2] += lo_bf(v.y) * w; acc[3] += hi_bf(v.y) * w;
    acc[4] += lo_bf(v.z) * w; acc[5] += hi_bf(v.z) * w;
    acc[6] += lo_bf(v.w) * w; acc[7] += hi_bf(v.w) * w;
}

// layer0: B[n] = bf16( relu(sum * in_norm[n] + b_g0) * out_norm[n] )
__global__ __launch_bounds__(256) void agg0_bf_kernel(
    const uint4* __restrict__ A, const int* __restrict__ off,
    const int* __restrict__ csr, const float* __restrict__ in_norm,
    const float* __restrict__ b_g0, const float* __restrict__ out_norm,
    uint4* __restrict__ B) {
    int idx = blockIdx.x * blockDim.x + threadIdx.x;
    int n = idx >> 4;
    if (n >= N_NODES) return;
    int j8 = idx & 15;
    int e0 = off[n], e1 = off[n + 1];
    float acc[8] = {0.f, 0.f, 0.f, 0.f, 0.f, 0.f, 0.f, 0.f};
    for (int e = e0; e < e1; ++e) {
        int s = csr[e] & 0x7fffffff;
        acc8_add(acc, A[(size_t)s * 16 + j8]);
    }
    float innv = in_norm[n], onv = out_norm[n];
    const float* bg = b_g0 + j8 * 8;
    float r[8];
#pragma unroll
    for (int k = 0; k < 8; ++k)
        r[k] = fmaxf(acc[k] * innv + bg[k], 0.f) * onv;
    uint4 o;
    o.x = pack2(r[0], r[1]); o.y = pack2(r[2], r[3]);
    o.z = pack2(r[4], r[5]); o.w = pack2(r[6], r[7]);
    B[(size_t)n * 16 + j8] = o;
}

// plain sum: B[n] = bf16( sum A[src_e] )
__global__ __launch_bounds__(256) void agg1_bf_kernel(
    const uint4* __restrict__ A, const int* __restrict__ off,
    const int* __restrict__ csr, uint4* __restrict__ B) {
    int idx = blockIdx.x * blockDim.x + threadIdx.x;
    int n = idx >> 4;
    if (n >= N_NODES) return;
    int j8 = idx & 15;
    int e0 = off[n], e1 = off[n + 1];
    float acc[8] = {0.f, 0.f, 0.f, 0.f, 0.f, 0.f, 0.f, 0.f};
    for (int e = e0; e < e1; ++e) {
        int s = csr[e] & 0x7fffffff;
        acc8_add(acc, A[(size_t)s * 16 + j8]);
    }
    uint4 o;
    o.x = pack2(acc[0], acc[1]); o.y = pack2(acc[2], acc[3]);
    o.z = pack2(acc[4], acc[5]); o.w = pack2(acc[6], acc[7]);
    B[(size_t)n * 16 + j8] = o;
}

// final: out[n] = sum_fwd h[src]*wf + sum_bwd h[dst]   (fp32 output)
__global__ __launch_bounds__(256) void final_bf_kernel(
    const uint4* __restrict__ H,
    const int* __restrict__ off_in, const int* __restrict__ csr_src,
    const int* __restrict__ off_bwd, const int* __restrict__ csr_bnode,
    float4* __restrict__ out4) {
    int idx = blockIdx.x * blockDim.x + threadIdx.x;
    int n = idx >> 4;
    if (n >= N_NODES) return;
    int j8 = idx & 15;
    float acc[8] = {0.f, 0.f, 0.f, 0.f, 0.f, 0.f, 0.f, 0.f};
    int e0 = off_in[n], e1 = off_in[n + 1];
    for (int e = e0; e < e1; ++e) {
        int c = csr_src[e];
        int s = c & 0x7fffffff;
        float w = (c < 0) ? 2.0f : 1.0f;
        acc8_addw(acc, H[(size_t)s * 16 + j8], w);
    }
    int f0 = off_bwd[n], f1 = off_bwd[n + 1];
    for (int e = f0; e < f1; ++e) {
        int d = csr_bnode[e];
        acc8_add(acc, H[(size_t)d * 16 + j8]);
    }
    float4 o0 = {acc[0], acc[1], acc[2], acc[3]};
    float4 o1 = {acc[4], acc[5], acc[6], acc[7]};
    out4[(size_t)n * 32 + j8 * 2]     = o0;
    out4[(size_t)n * 32 + j8 * 2 + 1] = o1;
}

extern "C" void kernel_launch(void* const* d_in, const int* in_sizes, int n_in,
                              void* d_out, int out_size, void* d_ws, size_t ws_size,
                              hipStream_t stream) {
    const float* feat[4]  = {(const float*)d_in[0], (const float*)d_in[3],
                             (const float*)d_in[6], (const float*)d_in[9]};
    const float* W_fc[4]  = {(const float*)d_in[1], (const float*)d_in[4],
                             (const float*)d_in[7], (const float*)d_in[10]};
    const float* b_fc[4]  = {(const float*)d_in[2], (const float*)d_in[5],
                             (const float*)d_in[8], (const float*)d_in[11]};
    const int*   src      = (const int*)d_in[12];
    const int*   dst      = (const int*)d_in[13];
    const int*   efeat    = (const int*)d_in[14];
    const float* b_g0     = (const float*)d_in[15];
    const float* W_g1     = (const float*)d_in[16];
    const float* b_g1     = (const float*)d_in[17];
    float* out = (float*)d_out;

    // ---- workspace layout (16B-aligned blocks first) ----
    char* p = (char*)d_ws;
    unsigned short* Abf = (unsigned short*)p; p += (size_t)N_NODES * HDIM * 2;  // 12.8 MB
    unsigned short* Bbf = (unsigned short*)p; p += (size_t)N_NODES * HDIM * 2;  // 12.8 MB
    unsigned short* Wp0 = (unsigned short*)p; p += 8 * 4 * 64 * 8 * 2;  // 32 KB (D=128)
    unsigned short* Wp1 = (unsigned short*)p; p += 8 * 4 * 64 * 8 * 2;
    unsigned short* Wp2 = (unsigned short*)p; p += 8 * 2 * 64 * 8 * 2;  // 16 KB (D=64)
    unsigned short* Wp3 = (unsigned short*)p; p += 8 * 2 * 64 * 8 * 2;
    unsigned short* Wpg = (unsigned short*)p; p += 8 * 4 * 64 * 8 * 2;
    float* out_norm = (float*)p; p += (size_t)N_NODES * 4;
    float* in_norm  = (float*)p; p += (size_t)N_NODES * 4;
    int* deg_in    = (int*)p; p += (size_t)N_NODES * 4;
    int* deg_out   = (int*)p; p += (size_t)N_NODES * 4;
    int* cnt_bwd   = (int*)p; p += (size_t)N_NODES * 4;
    int* off_in    = (int*)p; p += (size_t)(N_NODES + 1) * 4;
    int* off_bwd   = (int*)p; p += (size_t)(N_NODES + 1) * 4;
    int* cur_in    = (int*)p; p += (size_t)N_NODES * 4;
    int* cur_bwd   = (int*)p; p += (size_t)N_NODES * 4;
    int* csr_src   = (int*)p; p += (size_t)E_EDGES * 4;
    int* csr_bnode = (int*)p; p += (size_t)E_EDGES * 4;
    int* tmpa      = (int*)p; p += (size_t)N_NODES * 4;
    int* tmpb      = (int*)p; p += (size_t)N_NODES * 4;
    int* bsumA     = (int*)p; p += 64 * 4;
    int* bsumB     = (int*)p; p += 64 * 4;
    int* boffA     = (int*)p; p += 64 * 4;
    int* boffB     = (int*)p; p += 64 * 4;

    // 1) CSR build + norms
    hipMemsetAsync(deg_in, 0, 3 * (size_t)N_NODES * sizeof(int), stream);
    count_kernel<<<(E_EDGES + 255) / 256, 256, 0, stream>>>(src, dst, efeat,
                                                            deg_in, deg_out, cnt_bwd);
    scan1_kernel<<<SCAN_NBLK, 256, 0, stream>>>(deg_in, cnt_bwd, tmpa, tmpb,
                                                bsumA, bsumB, N_NODES);
    scan2_kernel<<<1, 64, 0, stream>>>(bsumA, bsumB, boffA, boffB,
                                       off_in, off_bwd, SCAN_NBLK, N_NODES);
    scan3_kernel<<<SCAN_NBLK, 256, 0, stream>>>(tmpa, tmpb, boffA, boffB,
                                                deg_in, deg_out,
                                                off_in, off_bwd, cur_in, cur_bwd,
                                                out_norm, in_norm, N_NODES);
    fill_kernel<<<(E_EDGES + 255) / 256, 256, 0, stream>>>(src, dst, efeat,
                                                           cur_in, cur_bwd,
                                                           csr_src, csr_bnode);

    // 2) pack weights into MFMA fragment order (tiny)
    prepw_kernel<<<(8 * 4 * 64 + 255) / 256, 256, 0, stream>>>(W_fc[0], Wp0, 128);
    prepw_kernel<<<(8 * 4 * 64 + 255) / 256, 256, 0, stream>>>(W_fc[1], Wp1, 128);
    prepw_kernel<<<(8 * 2 * 64 + 255) / 256, 256, 0, stream>>>(W_fc[2], Wp2, 64);
    prepw_kernel<<<(8 * 2 * 64 + 255) / 256, 256, 0, stream>>>(W_fc[3], Wp3, 64);
    prepw_kernel<<<(8 * 4 * 64 + 255) / 256, 256, 0, stream>>>(W_g1, Wpg, 128);

    // 3) per-type FC (MFMA): Abf[type rows] = bf16((feat @ W + b) * out_norm)
    const int grid_fc = (N_PER + 63) / 64;
    mfma_gemm_kernel<128, 0, true><<<grid_fc, 256, 0, stream>>>(
        feat[0], Wp0, b_fc[0], out_norm + 0 * N_PER, Abf + (size_t)0 * N_PER * HDIM, N_PER);
    mfma_gemm_kernel<128, 0, true><<<grid_fc, 256, 0, stream>>>(
        feat[1], Wp1, b_fc[1], out_norm + 1 * N_PER, Abf + (size_t)1 * N_PER * HDIM, N_PER);
    mfma_gemm_kernel<64, 0, true><<<grid_fc, 256, 0, stream>>>(
        feat[2], Wp2, b_fc[2], out_norm + 2 * N_PER, Abf + (size_t)2 * N_PER * HDIM, N_PER);
    mfma_gemm_kernel<64, 0, true><<<grid_fc, 256, 0, stream>>>(
        feat[3], Wp3, b_fc[3], out_norm + 3 * N_PER, Abf + (size_t)3 * N_PER * HDIM, N_PER);

    const int grid_node = (N_NODES * 16 + 255) / 256;   // 16 lanes/node

    // 4) layer0 gather: Bbf = bf16(relu(sum(Abf[src])*in_norm + b_g0) * out_norm)
    agg0_bf_kernel<<<grid_node, 256, 0, stream>>>((const uint4*)Abf, off_in, csr_src,
                                                  in_norm, b_g0, out_norm, (uint4*)Bbf);
    // 5) layer1 gather: Abf = bf16(sum(Bbf[src]))
    agg1_bf_kernel<<<grid_node, 256, 0, stream>>>((const uint4*)Bbf, off_in, csr_src,
                                                  (uint4*)Abf);
    // 6) big GEMM (MFMA): Bbf = bf16(relu((Abf @ W_g1) * in_norm + b_g1))
    mfma_gemm_kernel<128, 1, false><<<(N_NODES + 63) / 64, 256, 0, stream>>>(
        Abf, Wpg, b_g1, in_norm, Bbf, N_NODES);

    // 7) final edge-typed gather into fp32 d_out
    final_bf_kernel<<<grid_node, 256, 0, stream>>>((const uint4*)Bbf,
                                                   off_in, csr_src,
                                                   off_bwd, csr_bnode,
                                                   (float4*)out);
}

// Round 6
// 338.794 us; speedup vs baseline: 2.2521x; 1.0742x over previous
//
#include <hip/hip_runtime.h>
#include <hip/hip_bf16.h>

#define N_NODES 50000
#define N_PER   12500
#define E_EDGES 600000
#define HDIM    128

typedef __attribute__((ext_vector_type(8))) short bfrag;   // 8 bf16 (4 VGPRs)
typedef __attribute__((ext_vector_type(4))) float ffrag;   // 4 fp32 acc

__device__ __forceinline__ unsigned short f2bf(float f) {
    union { float f; unsigned u; } x; x.f = f;
    unsigned r = x.u + 0x7fffu + ((x.u >> 16) & 1u);   // RTNE
    return (unsigned short)(r >> 16);
}
__device__ __forceinline__ float lo_bf(unsigned v) { return __uint_as_float(v << 16); }
__device__ __forceinline__ float hi_bf(unsigned v) { return __uint_as_float(v & 0xffff0000u); }
__device__ __forceinline__ unsigned pack2(float a, float b) {
    return (unsigned)f2bf(a) | ((unsigned)f2bf(b) << 16);
}
__device__ __forceinline__ float onrm_of(int deg) {
    return rsqrtf(fmaxf((float)deg, 1.0f));
}

__device__ __forceinline__ void acc8_add(float* acc, uint4 v) {
    acc[0] += lo_bf(v.x); acc[1] += hi_bf(v.x);
    acc[2] += lo_bf(v.y); acc[3] += hi_bf(v.y);
    acc[4] += lo_bf(v.z); acc[5] += hi_bf(v.z);
    acc[6] += lo_bf(v.w); acc[7] += hi_bf(v.w);
}
__device__ __forceinline__ void acc8_addw(float* acc, uint4 v, float w) {
    acc[0] += lo_bf(v.x) * w; acc[1] += hi_bf(v.x) * w;
    acc[2] += lo_bf(v.y) * w; acc[3] += hi_bf(v.y) * w;
    acc[4] += lo_bf(v.z) * w; acc[5] += hi_bf(v.z) * w;
    acc[6] += lo_bf(v.w) * w; acc[7] += hi_bf(v.w) * w;
}

// ---------------------------------------------------------------------------
// Graph build: atomic linked lists (1 exch per edge; no count/scan/fill).
//   in-list keyed by dst (payload src|flagbit31), bwd-list keyed by src
//   (payload = original dst[e] array). deg_out for out_norm.
// ---------------------------------------------------------------------------
__global__ void build_kernel(const int* __restrict__ src, const int* __restrict__ dst,
                             const int* __restrict__ ef,
                             int* __restrict__ head_in, int* __restrict__ head_b,
                             int* __restrict__ deg_out,
                             int* __restrict__ pack, int* __restrict__ nexti,
                             int* __restrict__ nextb) {
    int e = blockIdx.x * blockDim.x + threadIdx.x;
    if (e >= E_EDGES) return;
    int s = src[e], d = dst[e], t = ef[e];
    pack[e]  = s | ((t <= 4) ? 0x80000000 : 0);       // bit31: fwd weight == 2
    nexti[e] = atomicExch(&head_in[d], e);
    atomicAdd(&deg_out[s], 1);
    if (t == 6 || t == 14 || t == 30)
        nextb[e] = atomicExch(&head_b[s], e);
}

// ---------------------------------------------------------------------------
// Pack all 5 weight matrices into MFMA B-fragment order (bf16), one launch.
// Segment layout (threads / dst elem offsets):
//   seg0 W_fc0 D=128 [0,2048)    off 0
//   seg1 W_fc1 D=128 [2048,4096) off 16384
//   seg2 W_fc2 D=64  [4096,5120) off 32768
//   seg3 W_fc3 D=64  [5120,6144) off 40960
//   seg4 W_g1  D=128 [6144,8192) off 49152
// ---------------------------------------------------------------------------
__global__ void prepw_all_kernel(const float* __restrict__ W0, const float* __restrict__ W1,
                                 const float* __restrict__ W2, const float* __restrict__ W3,
                                 const float* __restrict__ Wg,
                                 unsigned short* __restrict__ Wp) {
    int tid = blockIdx.x * blockDim.x + threadIdx.x;
    if (tid >= 8192) return;
    const float* W; int D, base, off;
    if      (tid < 2048) { W = W0; D = 128; base = 0;    off = 0;     }
    else if (tid < 4096) { W = W1; D = 128; base = 2048; off = 16384; }
    else if (tid < 5120) { W = W2; D = 64;  base = 4096; off = 32768; }
    else if (tid < 6144) { W = W3; D = 64;  base = 5120; off = 40960; }
    else                 { W = Wg; D = 128; base = 6144; off = 49152; }
    int t2 = tid - base;
    int KT = D / 32;
    int l = t2 & 63;
    int tt = t2 >> 6;
    int kt = tt % KT, n0 = tt / KT;
    int n = n0 * 16 + (l & 15);
    int kb = kt * 32 + (l >> 4) * 8;
#pragma unroll
    for (int j = 0; j < 8; ++j)
        Wp[(size_t)off + (size_t)t2 * 8 + j] = f2bf(W[(size_t)(kb + j) * 128 + n]);
}

// ---------------------------------------------------------------------------
// FC MFMA GEMM: out = bf16(X(rows x D) @ W + bias); X is fp32.
// Wave computes a 16-row strip, 8 col-tiles of 16x16.
// ---------------------------------------------------------------------------
template<int D>
__global__ __launch_bounds__(256) void fc_mfma_kernel(
    const float* __restrict__ X,
    const unsigned short* __restrict__ Wp,
    const float* __restrict__ bias,
    unsigned short* __restrict__ outbf,
    int rows)
{
    constexpr int KT = D / 32;
    const int lane = threadIdx.x & 63;
    const int wave = threadIdx.x >> 6;
    const int m = lane & 15, q = lane >> 4;
    const int rbase = blockIdx.x * 64 + wave * 16;
    const int row = rbase + m;

    bfrag afr[KT];
#pragma unroll
    for (int kt = 0; kt < KT; ++kt) {
        bfrag a;
        if (row < rows) {
            const float* xp = X + (size_t)row * D + kt * 32 + q * 8;
            float4 u0 = *(const float4*)xp;
            float4 u1 = *(const float4*)(xp + 4);
            a[0] = (short)f2bf(u0.x); a[1] = (short)f2bf(u0.y);
            a[2] = (short)f2bf(u0.z); a[3] = (short)f2bf(u0.w);
            a[4] = (short)f2bf(u1.x); a[5] = (short)f2bf(u1.y);
            a[6] = (short)f2bf(u1.z); a[7] = (short)f2bf(u1.w);
        } else {
#pragma unroll
            for (int t = 0; t < 8; ++t) a[t] = 0;
        }
        afr[kt] = a;
    }

    ffrag acc[8];
#pragma unroll
    for (int n0 = 0; n0 < 8; ++n0)
#pragma unroll
        for (int t = 0; t < 4; ++t) acc[n0][t] = 0.f;

#pragma unroll
    for (int n0 = 0; n0 < 8; ++n0)
#pragma unroll
        for (int kt = 0; kt < KT; ++kt) {
            bfrag bfr = *(const bfrag*)(Wp + ((size_t)(n0 * KT + kt) * 64 + lane) * 8);
            acc[n0] = __builtin_amdgcn_mfma_f32_16x16x32_bf16(afr[kt], bfr, acc[n0], 0, 0, 0);
        }

#pragma unroll
    for (int n0 = 0; n0 < 8; ++n0) {
        const int col = n0 * 16 + m;
        const float bj = bias[col];
#pragma unroll
        for (int r = 0; r < 4; ++r) {
            int orow = rbase + q * 4 + r;
            if (orow < rows)
                outbf[(size_t)orow * 128 + col] = f2bf(acc[n0][r] + bj);
        }
    }
}

// ---------------------------------------------------------------------------
// Layer-0 gather (chain walk): 16 lanes/node, uint4 per lane.
//   B[n] = bf16( relu( (sum_e A[s_e]*onrm(s_e)) * inrm(n) + b_g0 ) )
//   also stores inrm(n) for the layer-1 GEMM epilogue.
// ---------------------------------------------------------------------------
__global__ __launch_bounds__(256) void agg0_kernel(
    const uint4* __restrict__ A, const int* __restrict__ head,
    const int* __restrict__ nexti, const int* __restrict__ pack,
    const int* __restrict__ deg_out, const float* __restrict__ b_g0,
    uint4* __restrict__ B, float* __restrict__ inrm_arr) {
    int idx = blockIdx.x * blockDim.x + threadIdx.x;
    int n = idx >> 4;
    if (n >= N_NODES) return;
    int j8 = idx & 15;
    float acc[8] = {0.f, 0.f, 0.f, 0.f, 0.f, 0.f, 0.f, 0.f};
    int cnt = 0;
    int e = head[n];
    while (e >= 0) {
        int s = pack[e] & 0x7fffffff;
        float on = onrm_of(deg_out[s]);
        acc8_addw(acc, A[(size_t)s * 16 + j8], on);
        ++cnt;
        e = nexti[e];
    }
    float inr = onrm_of(cnt);
    const float* bg = b_g0 + j8 * 8;
    float r[8];
#pragma unroll
    for (int k = 0; k < 8; ++k)
        r[k] = fmaxf(acc[k] * inr + bg[k], 0.f);
    uint4 o;
    o.x = pack2(r[0], r[1]); o.y = pack2(r[2], r[3]);
    o.z = pack2(r[4], r[5]); o.w = pack2(r[6], r[7]);
    B[(size_t)n * 16 + j8] = o;
    if (j8 == 0) inrm_arr[n] = inr;
}

// ---------------------------------------------------------------------------
// Fused layer-1 gather + MFMA GEMM:
//   per wave: 16 nodes; lane (m,q) walks node (rbase+m)'s chain accumulating
//   k = kt*32+q*8+j of sum_e B[s_e]*onrm(s_e) directly into A-fragment regs;
//   then 16 MFMAs with W_g1; epilogue relu(c*inrm[row]+b_g1) -> bf16.
// ---------------------------------------------------------------------------
__global__ __launch_bounds__(256) void gemm1_fused_kernel(
    const unsigned short* __restrict__ Bbf,
    const int* __restrict__ head, const int* __restrict__ nexti,
    const int* __restrict__ pack, const int* __restrict__ deg_out,
    const unsigned short* __restrict__ Wp, const float* __restrict__ bias,
    const float* __restrict__ inrm_arr, unsigned short* __restrict__ outbf)
{
    const int lane = threadIdx.x & 63;
    const int wave = threadIdx.x >> 6;
    const int m = lane & 15, q = lane >> 4;
    const int rbase = blockIdx.x * 64 + wave * 16;
    const int node = rbase + m;

    float ga[32];
#pragma unroll
    for (int i = 0; i < 32; ++i) ga[i] = 0.f;

    if (node < N_NODES) {
        int e = head[node];
        while (e >= 0) {
            int s = pack[e] & 0x7fffffff;
            float on = onrm_of(deg_out[s]);
            const uint4* rp = (const uint4*)(Bbf + (size_t)s * 128);
#pragma unroll
            for (int kt = 0; kt < 4; ++kt) {
                uint4 v = rp[kt * 4 + q];
                ga[kt * 8 + 0] += lo_bf(v.x) * on; ga[kt * 8 + 1] += hi_bf(v.x) * on;
                ga[kt * 8 + 2] += lo_bf(v.y) * on; ga[kt * 8 + 3] += hi_bf(v.y) * on;
                ga[kt * 8 + 4] += lo_bf(v.z) * on; ga[kt * 8 + 5] += hi_bf(v.z) * on;
                ga[kt * 8 + 6] += lo_bf(v.w) * on; ga[kt * 8 + 7] += hi_bf(v.w) * on;
            }
            e = nexti[e];
        }
    }

    bfrag afr[4];
#pragma unroll
    for (int kt = 0; kt < 4; ++kt)
#pragma unroll
        for (int j = 0; j < 8; ++j)
            afr[kt][j] = (short)f2bf(ga[kt * 8 + j]);

    ffrag acc[8];
#pragma unroll
    for (int n0 = 0; n0 < 8; ++n0)
#pragma unroll
        for (int t = 0; t < 4; ++t) acc[n0][t] = 0.f;

#pragma unroll
    for (int n0 = 0; n0 < 8; ++n0)
#pragma unroll
        for (int kt = 0; kt < 4; ++kt) {
            bfrag bfr = *(const bfrag*)(Wp + ((size_t)(n0 * 4 + kt) * 64 + lane) * 8);
            acc[n0] = __builtin_amdgcn_mfma_f32_16x16x32_bf16(afr[kt], bfr, acc[n0], 0, 0, 0);
        }

    float ir[4];
#pragma unroll
    for (int r = 0; r < 4; ++r) {
        int orow = rbase + q * 4 + r;
        ir[r] = (orow < N_NODES) ? inrm_arr[orow] : 0.f;
    }
#pragma unroll
    for (int n0 = 0; n0 < 8; ++n0) {
        const int col = n0 * 16 + m;
        const float bj = bias[col];
#pragma unroll
        for (int r = 0; r < 4; ++r) {
            int orow = rbase + q * 4 + r;
            if (orow < N_NODES)
                outbf[(size_t)orow * 128 + col] = f2bf(fmaxf(acc[n0][r] * ir[r] + bj, 0.f));
        }
    }
}

// ---------------------------------------------------------------------------
// Final: out[n] = sum_fwd h[src]*wf + sum_bwd h[dst]   (fp32 output)
// ---------------------------------------------------------------------------
__global__ __launch_bounds__(256) void final_kernel(
    const uint4* __restrict__ H,
    const int* __restrict__ head, const int* __restrict__ nexti,
    const int* __restrict__ pack,
    const int* __restrict__ headb, const int* __restrict__ nextb,
    const int* __restrict__ dstArr,
    float4* __restrict__ out4) {
    int idx = blockIdx.x * blockDim.x + threadIdx.x;
    int n = idx >> 4;
    if (n >= N_NODES) return;
    int j8 = idx & 15;
    float acc[8] = {0.f, 0.f, 0.f, 0.f, 0.f, 0.f, 0.f, 0.f};
    int e = head[n];
    while (e >= 0) {
        int c = pack[e];
        int s = c & 0x7fffffff;
        float w = (c < 0) ? 2.0f : 1.0f;
        acc8_addw(acc, H[(size_t)s * 16 + j8], w);
        e = nexti[e];
    }
    e = headb[n];
    while (e >= 0) {
        int d = dstArr[e];
        acc8_add(acc, H[(size_t)d * 16 + j8]);
        e = nextb[e];
    }
    float4 o0 = {acc[0], acc[1], acc[2], acc[3]};
    float4 o1 = {acc[4], acc[5], acc[6], acc[7]};
    out4[(size_t)n * 32 + j8 * 2]     = o0;
    out4[(size_t)n * 32 + j8 * 2 + 1] = o1;
}

extern "C" void kernel_launch(void* const* d_in, const int* in_sizes, int n_in,
                              void* d_out, int out_size, void* d_ws, size_t ws_size,
                              hipStream_t stream) {
    const float* feat[4]  = {(const float*)d_in[0], (const float*)d_in[3],
                             (const float*)d_in[6], (const float*)d_in[9]};
    const float* W_fc[4]  = {(const float*)d_in[1], (const float*)d_in[4],
                             (const float*)d_in[7], (const float*)d_in[10]};
    const float* b_fc[4]  = {(const float*)d_in[2], (const float*)d_in[5],
                             (const float*)d_in[8], (const float*)d_in[11]};
    const int*   src      = (const int*)d_in[12];
    const int*   dst      = (const int*)d_in[13];
    const int*   efeat    = (const int*)d_in[14];
    const float* b_g0     = (const float*)d_in[15];
    const float* W_g1     = (const float*)d_in[16];
    const float* b_g1     = (const float*)d_in[17];
    float* out = (float*)d_out;

    // ---- workspace layout (16B blocks first), ~34 MB ----
    char* p = (char*)d_ws;
    unsigned short* Abf = (unsigned short*)p; p += (size_t)N_NODES * HDIM * 2;  // 12.8 MB
    unsigned short* Bbf = (unsigned short*)p; p += (size_t)N_NODES * HDIM * 2;  // 12.8 MB
    unsigned short* Wp  = (unsigned short*)p; p += (size_t)65536 * 2;           // 128 KB
    int* pack    = (int*)p; p += (size_t)E_EDGES * 4;    // 2.4 MB
    int* nexti   = (int*)p; p += (size_t)E_EDGES * 4;    // 2.4 MB
    int* nextb   = (int*)p; p += (size_t)E_EDGES * 4;    // 2.4 MB
    int* head_in = (int*)p; p += (size_t)N_NODES * 4;    // 200 KB  (adjacent to
    int* head_b  = (int*)p; p += (size_t)N_NODES * 4;    //  head_b: one memset)
    int* deg_out = (int*)p; p += (size_t)N_NODES * 4;
    float* inrm_arr = (float*)p; p += (size_t)N_NODES * 4;

    const unsigned short* Wp0 = Wp;
    const unsigned short* Wp1 = Wp + 16384;
    const unsigned short* Wp2 = Wp + 32768;
    const unsigned short* Wp3 = Wp + 40960;
    const unsigned short* Wpg = Wp + 49152;

    // 1) init heads (-1) and deg_out (0), then build linked lists
    hipMemsetAsync(head_in, 0xFF, 2 * (size_t)N_NODES * sizeof(int), stream);
    hipMemsetAsync(deg_out, 0, (size_t)N_NODES * sizeof(int), stream);
    build_kernel<<<(E_EDGES + 255) / 256, 256, 0, stream>>>(
        src, dst, efeat, head_in, head_b, deg_out, pack, nexti, nextb);

    // 2) pack all weights (one tiny launch)
    prepw_all_kernel<<<32, 256, 0, stream>>>(W_fc[0], W_fc[1], W_fc[2], W_fc[3], W_g1, Wp);

    // 3) per-type FC (MFMA): Abf = bf16(feat @ W + b)   (no norm scale)
    const int grid_fc = (N_PER + 63) / 64;
    fc_mfma_kernel<128><<<grid_fc, 256, 0, stream>>>(
        feat[0], Wp0, b_fc[0], Abf + (size_t)0 * N_PER * HDIM, N_PER);
    fc_mfma_kernel<128><<<grid_fc, 256, 0, stream>>>(
        feat[1], Wp1, b_fc[1], Abf + (size_t)1 * N_PER * HDIM, N_PER);
    fc_mfma_kernel<64><<<grid_fc, 256, 0, stream>>>(
        feat[2], Wp2, b_fc[2], Abf + (size_t)2 * N_PER * HDIM, N_PER);
    fc_mfma_kernel<64><<<grid_fc, 256, 0, stream>>>(
        feat[3], Wp3, b_fc[3], Abf + (size_t)3 * N_PER * HDIM, N_PER);

    const int grid_node = (N_NODES * 16 + 255) / 256;   // 16 lanes/node

    // 4) layer0 gather: Bbf = bf16(relu(sum(Abf[s]*onrm[s]) * inrm + b_g0)); save inrm
    agg0_kernel<<<grid_node, 256, 0, stream>>>(
        (const uint4*)Abf, head_in, nexti, pack, deg_out, b_g0,
        (uint4*)Bbf, inrm_arr);

    // 5) fused layer1 gather + GEMM: Abf = bf16(relu((sum Bbf[s]*onrm[s]) @ W_g1 * inrm + b_g1))
    gemm1_fused_kernel<<<(N_NODES + 63) / 64, 256, 0, stream>>>(
        Bbf, head_in, nexti, pack, deg_out, Wpg, b_g1, inrm_arr, Abf);

    // 6) final edge-typed gather into fp32 d_out
    final_kernel<<<grid_node, 256, 0, stream>>>(
        (const uint4*)Abf, head_in, nexti, pack, head_b, nextb, dst,
        (float4*)out);
}

// Round 7
// 299.212 us; speedup vs baseline: 2.5500x; 1.1323x over previous
//
#include <hip/hip_runtime.h>
#include <hip/hip_bf16.h>

#define N_NODES 50000
#define N_PER   12500
#define E_EDGES 600000
#define HDIM    128

#define NBLK_BUILD ((E_EDGES + 255) / 256)        // 2344
#define NBLK_FC    ((N_PER + 63) / 64)            // 196

typedef __attribute__((ext_vector_type(8))) short bfrag;   // 8 bf16 (4 VGPRs)
typedef __attribute__((ext_vector_type(4))) float ffrag;   // 4 fp32 acc

__device__ __forceinline__ unsigned short f2bf(float f) {
    union { float f; unsigned u; } x; x.f = f;
    unsigned r = x.u + 0x7fffu + ((x.u >> 16) & 1u);   // RTNE
    return (unsigned short)(r >> 16);
}
__device__ __forceinline__ float lo_bf(unsigned v) { return __uint_as_float(v << 16); }
__device__ __forceinline__ float hi_bf(unsigned v) { return __uint_as_float(v & 0xffff0000u); }
__device__ __forceinline__ unsigned pack2(float a, float b) {
    return (unsigned)f2bf(a) | ((unsigned)f2bf(b) << 16);
}
__device__ __forceinline__ float onrm_of(int deg) {
    return rsqrtf(fmaxf((float)deg, 1.0f));
}

__device__ __forceinline__ void acc8_add(float* acc, uint4 v) {
    acc[0] += lo_bf(v.x); acc[1] += hi_bf(v.x);
    acc[2] += lo_bf(v.y); acc[3] += hi_bf(v.y);
    acc[4] += lo_bf(v.z); acc[5] += hi_bf(v.z);
    acc[6] += lo_bf(v.w); acc[7] += hi_bf(v.w);
}
__device__ __forceinline__ void acc8_addw(float* acc, uint4 v, float w) {
    acc[0] += lo_bf(v.x) * w; acc[1] += hi_bf(v.x) * w;
    acc[2] += lo_bf(v.y) * w; acc[3] += hi_bf(v.y) * w;
    acc[4] += lo_bf(v.z) * w; acc[5] += hi_bf(v.z) * w;
    acc[6] += lo_bf(v.w) * w; acc[7] += hi_bf(v.w) * w;
}

// ---------------------------------------------------------------------------
// K0: weight fragment packing (blocks 0..31) + head/deg init (blocks 32..178).
//   Wp segments: fc0 @0, fc1 @16384, fc2 @32768, fc3 @40960, g1 @49152.
//   init region: head_in[50k]=-1, head_b[50k]=-1, deg_out[50k]=0 (contiguous).
// ---------------------------------------------------------------------------
__global__ __launch_bounds__(256) void prep_kernel(
    const float* __restrict__ W0, const float* __restrict__ W1,
    const float* __restrict__ W2, const float* __restrict__ W3,
    const float* __restrict__ Wg,
    unsigned short* __restrict__ Wp, int* __restrict__ initp) {
    int b = blockIdx.x;
    if (b < 32) {
        int tid = b * 256 + threadIdx.x;
        const float* W; int D, base, off;
        if      (tid < 2048) { W = W0; D = 128; base = 0;    off = 0;     }
        else if (tid < 4096) { W = W1; D = 128; base = 2048; off = 16384; }
        else if (tid < 5120) { W = W2; D = 64;  base = 4096; off = 32768; }
        else if (tid < 6144) { W = W3; D = 64;  base = 5120; off = 40960; }
        else                 { W = Wg; D = 128; base = 6144; off = 49152; }
        int t2 = tid - base;
        int KT = D / 32;
        int l = t2 & 63;
        int tt = t2 >> 6;
        int kt = tt % KT, n0 = tt / KT;
        int n = n0 * 16 + (l & 15);
        int kb = kt * 32 + (l >> 4) * 8;
#pragma unroll
        for (int j = 0; j < 8; ++j)
            Wp[(size_t)off + (size_t)t2 * 8 + j] = f2bf(W[(size_t)(kb + j) * 128 + n]);
    } else {
        int blk = b - 32;
#pragma unroll
        for (int k = 0; k < 4; ++k) {
            int i = blk * 1024 + k * 256 + threadIdx.x;
            if (i < 3 * N_NODES)
                initp[i] = (i < 2 * N_NODES) ? -1 : 0;
        }
    }
}

// ---------------------------------------------------------------------------
// FC MFMA body: out = bf16(X(rows x D) @ W + bias); X fp32.
// ---------------------------------------------------------------------------
template<int D>
__device__ __forceinline__ void fc_body(
    int blk, int tid,
    const float* __restrict__ X,
    const unsigned short* __restrict__ Wp,
    const float* __restrict__ bias,
    unsigned short* __restrict__ outbf,
    int rows)
{
    constexpr int KT = D / 32;
    const int lane = tid & 63;
    const int wave = tid >> 6;
    const int m = lane & 15, q = lane >> 4;
    const int rbase = blk * 64 + wave * 16;
    const int row = rbase + m;

    bfrag afr[KT];
#pragma unroll
    for (int kt = 0; kt < KT; ++kt) {
        bfrag a;
        if (row < rows) {
            const float* xp = X + (size_t)row * D + kt * 32 + q * 8;
            float4 u0 = *(const float4*)xp;
            float4 u1 = *(const float4*)(xp + 4);
            a[0] = (short)f2bf(u0.x); a[1] = (short)f2bf(u0.y);
            a[2] = (short)f2bf(u0.z); a[3] = (short)f2bf(u0.w);
            a[4] = (short)f2bf(u1.x); a[5] = (short)f2bf(u1.y);
            a[6] = (short)f2bf(u1.z); a[7] = (short)f2bf(u1.w);
        } else {
#pragma unroll
            for (int t = 0; t < 8; ++t) a[t] = 0;
        }
        afr[kt] = a;
    }

    ffrag acc[8];
#pragma unroll
    for (int n0 = 0; n0 < 8; ++n0)
#pragma unroll
        for (int t = 0; t < 4; ++t) acc[n0][t] = 0.f;

#pragma unroll
    for (int n0 = 0; n0 < 8; ++n0)
#pragma unroll
        for (int kt = 0; kt < KT; ++kt) {
            bfrag bfr = *(const bfrag*)(Wp + ((size_t)(n0 * KT + kt) * 64 + lane) * 8);
            acc[n0] = __builtin_amdgcn_mfma_f32_16x16x32_bf16(afr[kt], bfr, acc[n0], 0, 0, 0);
        }

#pragma unroll
    for (int n0 = 0; n0 < 8; ++n0) {
        const int col = n0 * 16 + m;
        const float bj = bias[col];
#pragma unroll
        for (int r = 0; r < 4; ++r) {
            int orow = rbase + q * 4 + r;
            if (orow < rows)
                outbf[(size_t)orow * 128 + col] = f2bf(acc[n0][r] + bj);
        }
    }
}

// ---------------------------------------------------------------------------
// K1 mega-kernel: blocks [0,2344) build linked lists (atomic-bound);
//   blocks [2344, 2344+4*196) run the four FC GEMMs (MFMA-bound).
//   Independent work — overlapping fills idle pipes during the atomic phase.
// ---------------------------------------------------------------------------
__global__ __launch_bounds__(256) void mega_kernel(
    const int* __restrict__ src, const int* __restrict__ dst,
    const int* __restrict__ ef,
    int* __restrict__ head_in, int* __restrict__ head_b,
    int* __restrict__ deg_out,
    int* __restrict__ pack, int* __restrict__ nexti, int* __restrict__ nextb,
    const float* __restrict__ f0, const float* __restrict__ f1,
    const float* __restrict__ f2, const float* __restrict__ f3,
    const unsigned short* __restrict__ Wp,
    const float* __restrict__ b0, const float* __restrict__ b1,
    const float* __restrict__ b2, const float* __restrict__ b3,
    unsigned short* __restrict__ Abf)
{
    const int b = blockIdx.x;
    if (b < NBLK_BUILD) {
        int e = b * 256 + threadIdx.x;
        if (e >= E_EDGES) return;
        int s = src[e], d = dst[e], t = ef[e];
        pack[e]  = s | ((t <= 4) ? 0x80000000 : 0);   // bit31: fwd weight == 2
        nexti[e] = atomicExch(&head_in[d], e);
        atomicAdd(&deg_out[s], 1);
        if (t == 6 || t == 14 || t == 30)
            nextb[e] = atomicExch(&head_b[s], e);
    } else {
        int fb = b - NBLK_BUILD;
        int which = fb / NBLK_FC;
        int blk = fb - which * NBLK_FC;
        if (which == 0)
            fc_body<128>(blk, threadIdx.x, f0, Wp,         b0, Abf + (size_t)0 * N_PER * HDIM, N_PER);
        else if (which == 1)
            fc_body<128>(blk, threadIdx.x, f1, Wp + 16384, b1, Abf + (size_t)1 * N_PER * HDIM, N_PER);
        else if (which == 2)
            fc_body<64>(blk, threadIdx.x, f2, Wp + 32768, b2, Abf + (size_t)2 * N_PER * HDIM, N_PER);
        else
            fc_body<64>(blk, threadIdx.x, f3, Wp + 40960, b3, Abf + (size_t)3 * N_PER * HDIM, N_PER);
    }
}

// ---------------------------------------------------------------------------
// K2: layer-0 gather (chain walk), 16 lanes/node.
//   B[n] = bf16( relu( (sum_e A[s_e]*onrm(s_e)) * inrm(n) + b_g0 ) * onrm(n) )
//   (onrm(n) folded in so K3's gather is a plain sum); saves inrm(n).
// ---------------------------------------------------------------------------
__global__ __launch_bounds__(256) void agg0_kernel(
    const uint4* __restrict__ A, const int* __restrict__ head,
    const int* __restrict__ nexti, const int* __restrict__ pack,
    const int* __restrict__ deg_out, const float* __restrict__ b_g0,
    uint4* __restrict__ B, float* __restrict__ inrm_arr) {
    int idx = blockIdx.x * blockDim.x + threadIdx.x;
    int n = idx >> 4;
    if (n >= N_NODES) return;
    int j8 = idx & 15;
    float acc[8] = {0.f, 0.f, 0.f, 0.f, 0.f, 0.f, 0.f, 0.f};
    int cnt = 0;
    int e = head[n];
    while (e >= 0) {
        int s = pack[e] & 0x7fffffff;
        float on = onrm_of(deg_out[s]);
        acc8_addw(acc, A[(size_t)s * 16 + j8], on);
        ++cnt;
        e = nexti[e];
    }
    float inr = onrm_of(cnt);
    float onr = onrm_of(deg_out[n]);
    const float* bg = b_g0 + j8 * 8;
    float r[8];
#pragma unroll
    for (int k = 0; k < 8; ++k)
        r[k] = fmaxf(acc[k] * inr + bg[k], 0.f) * onr;
    uint4 o;
    o.x = pack2(r[0], r[1]); o.y = pack2(r[2], r[3]);
    o.z = pack2(r[4], r[5]); o.w = pack2(r[6], r[7]);
    B[(size_t)n * 16 + j8] = o;
    if (j8 == 0) inrm_arr[n] = inr;
}

// ---------------------------------------------------------------------------
// K3: fused layer-1 gather + MFMA GEMM (plain chain sum; onrm pre-folded).
// ---------------------------------------------------------------------------
__global__ __launch_bounds__(256) void gemm1_fused_kernel(
    const unsigned short* __restrict__ Bbf,
    const int* __restrict__ head, const int* __restrict__ nexti,
    const int* __restrict__ pack,
    const unsigned short* __restrict__ Wp, const float* __restrict__ bias,
    const float* __restrict__ inrm_arr, unsigned short* __restrict__ outbf)
{
    const int lane = threadIdx.x & 63;
    const int wave = threadIdx.x >> 6;
    const int m = lane & 15, q = lane >> 4;
    const int rbase = blockIdx.x * 64 + wave * 16;
    const int node = rbase + m;

    float ga[32];
#pragma unroll
    for (int i = 0; i < 32; ++i) ga[i] = 0.f;

    if (node < N_NODES) {
        int e = head[node];
        while (e >= 0) {
            int s = pack[e] & 0x7fffffff;
            const uint4* rp = (const uint4*)(Bbf + (size_t)s * 128);
#pragma unroll
            for (int kt = 0; kt < 4; ++kt) {
                uint4 v = rp[kt * 4 + q];
                ga[kt * 8 + 0] += lo_bf(v.x); ga[kt * 8 + 1] += hi_bf(v.x);
                ga[kt * 8 + 2] += lo_bf(v.y); ga[kt * 8 + 3] += hi_bf(v.y);
                ga[kt * 8 + 4] += lo_bf(v.z); ga[kt * 8 + 5] += hi_bf(v.z);
                ga[kt * 8 + 6] += lo_bf(v.w); ga[kt * 8 + 7] += hi_bf(v.w);
            }
            e = nexti[e];
        }
    }

    bfrag afr[4];
#pragma unroll
    for (int kt = 0; kt < 4; ++kt)
#pragma unroll
        for (int j = 0; j < 8; ++j)
            afr[kt][j] = (short)f2bf(ga[kt * 8 + j]);

    ffrag acc[8];
#pragma unroll
    for (int n0 = 0; n0 < 8; ++n0)
#pragma unroll
        for (int t = 0; t < 4; ++t) acc[n0][t] = 0.f;

#pragma unroll
    for (int n0 = 0; n0 < 8; ++n0)
#pragma unroll
        for (int kt = 0; kt < 4; ++kt) {
            bfrag bfr = *(const bfrag*)(Wp + ((size_t)(n0 * 4 + kt) * 64 + lane) * 8);
            acc[n0] = __builtin_amdgcn_mfma_f32_16x16x32_bf16(afr[kt], bfr, acc[n0], 0, 0, 0);
        }

    float ir[4];
#pragma unroll
    for (int r = 0; r < 4; ++r) {
        int orow = rbase + q * 4 + r;
        ir[r] = (orow < N_NODES) ? inrm_arr[orow] : 0.f;
    }
#pragma unroll
    for (int n0 = 0; n0 < 8; ++n0) {
        const int col = n0 * 16 + m;
        const float bj = bias[col];
#pragma unroll
        for (int r = 0; r < 4; ++r) {
            int orow = rbase + q * 4 + r;
            if (orow < N_NODES)
                outbf[(size_t)orow * 128 + col] = f2bf(fmaxf(acc[n0][r] * ir[r] + bj, 0.f));
        }
    }
}

// ---------------------------------------------------------------------------
// K4: final edge-typed gather -> fp32 out.
// ---------------------------------------------------------------------------
__global__ __launch_bounds__(256) void final_kernel(
    const uint4* __restrict__ H,
    const int* __restrict__ head, const int* __restrict__ nexti,
    const int* __restrict__ pack,
    const int* __restrict__ headb, const int* __restrict__ nextb,
    const int* __restrict__ dstArr,
    float4* __restrict__ out4) {
    int idx = blockIdx.x * blockDim.x + threadIdx.x;
    int n = idx >> 4;
    if (n >= N_NODES) return;
    int j8 = idx & 15;
    float acc[8] = {0.f, 0.f, 0.f, 0.f, 0.f, 0.f, 0.f, 0.f};
    int e = head[n];
    while (e >= 0) {
        int c = pack[e];
        int s = c & 0x7fffffff;
        float w = (c < 0) ? 2.0f : 1.0f;
        acc8_addw(acc, H[(size_t)s * 16 + j8], w);
        e = nexti[e];
    }
    e = headb[n];
    while (e >= 0) {
        int d = dstArr[e];
        acc8_add(acc, H[(size_t)d * 16 + j8]);
        e = nextb[e];
    }
    float4 o0 = {acc[0], acc[1], acc[2], acc[3]};
    float4 o1 = {acc[4], acc[5], acc[6], acc[7]};
    out4[(size_t)n * 32 + j8 * 2]     = o0;
    out4[(size_t)n * 32 + j8 * 2 + 1] = o1;
}

extern "C" void kernel_launch(void* const* d_in, const int* in_sizes, int n_in,
                              void* d_out, int out_size, void* d_ws, size_t ws_size,
                              hipStream_t stream) {
    const float* feat[4]  = {(const float*)d_in[0], (const float*)d_in[3],
                             (const float*)d_in[6], (const float*)d_in[9]};
    const float* W_fc[4]  = {(const float*)d_in[1], (const float*)d_in[4],
                             (const float*)d_in[7], (const float*)d_in[10]};
    const float* b_fc[4]  = {(const float*)d_in[2], (const float*)d_in[5],
                             (const float*)d_in[8], (const float*)d_in[11]};
    const int*   src      = (const int*)d_in[12];
    const int*   dst      = (const int*)d_in[13];
    const int*   efeat    = (const int*)d_in[14];
    const float* b_g0     = (const float*)d_in[15];
    const float* W_g1     = (const float*)d_in[16];
    const float* b_g1     = (const float*)d_in[17];
    float* out = (float*)d_out;

    // ---- workspace layout (16B blocks first), ~34 MB ----
    char* p = (char*)d_ws;
    unsigned short* Abf = (unsigned short*)p; p += (size_t)N_NODES * HDIM * 2;  // 12.8 MB
    unsigned short* Bbf = (unsigned short*)p; p += (size_t)N_NODES * HDIM * 2;  // 12.8 MB
    unsigned short* Wp  = (unsigned short*)p; p += (size_t)65536 * 2;           // 128 KB
    int* pack    = (int*)p; p += (size_t)E_EDGES * 4;    // 2.4 MB
    int* nexti   = (int*)p; p += (size_t)E_EDGES * 4;    // 2.4 MB
    int* nextb   = (int*)p; p += (size_t)E_EDGES * 4;    // 2.4 MB
    int* head_in = (int*)p; p += (size_t)N_NODES * 4;    // contiguous init
    int* head_b  = (int*)p; p += (size_t)N_NODES * 4;    //  region: head_in,
    int* deg_out = (int*)p; p += (size_t)N_NODES * 4;    //  head_b, deg_out
    float* inrm_arr = (float*)p; p += (size_t)N_NODES * 4;

    const unsigned short* Wpg = Wp + 49152;

    // K0: weight packing + head/deg init (replaces 2 memsets + prepw launch)
    prep_kernel<<<32 + (3 * N_NODES + 1023) / 1024, 256, 0, stream>>>(
        W_fc[0], W_fc[1], W_fc[2], W_fc[3], W_g1, Wp, head_in);

    // K1: fused graph build (atomics) + 4 FC GEMMs (MFMA) — independent work
    mega_kernel<<<NBLK_BUILD + 4 * NBLK_FC, 256, 0, stream>>>(
        src, dst, efeat, head_in, head_b, deg_out, pack, nexti, nextb,
        feat[0], feat[1], feat[2], feat[3], Wp,
        b_fc[0], b_fc[1], b_fc[2], b_fc[3], Abf);

    const int grid_node = (N_NODES * 16 + 255) / 256;   // 16 lanes/node

    // K2: layer0 gather, onrm folded into output; saves inrm
    agg0_kernel<<<grid_node, 256, 0, stream>>>(
        (const uint4*)Abf, head_in, nexti, pack, deg_out, b_g0,
        (uint4*)Bbf, inrm_arr);

    // K3: fused layer1 gather + GEMM
    gemm1_fused_kernel<<<(N_NODES + 63) / 64, 256, 0, stream>>>(
        Bbf, head_in, nexti, pack, Wpg, b_g1, inrm_arr, Abf);

    // K4: final edge-typed gather into fp32 d_out
    final_kernel<<<grid_node, 256, 0, stream>>>(
        (const uint4*)Abf, head_in, nexti, pack, head_b, nextb, dst,
        (float4*)out);
}